// Round 1
// baseline (790.851 us; speedup 1.0000x reference)
//
#include <hip/hip_runtime.h>

#define N_NODES  20000
#define N_EDGES  200000
#define N_SEG    16
#define EXTENT   32
#define N_PATHS  64
#define OP_SIZE  (N_SEG * EXTENT)   // 512

// ---------------- CSR build: histogram -> scan -> scatter ----------------

__global__ void k_hist(const int* __restrict__ dst, int* __restrict__ offsets) {
    int e = blockIdx.x * blockDim.x + threadIdx.x;
    if (e < N_EDGES) atomicAdd(&offsets[dst[e]], 1);
}

// single block, in-place exclusive scan of offsets[0..N_NODES)
__global__ void k_scan(int* __restrict__ offsets) {
    __shared__ int sums[256];
    const int T = 256;
    int tid = threadIdx.x;
    int chunk = (N_NODES + T - 1) / T;            // 79
    int lo = tid * chunk;
    int hi = lo + chunk; if (hi > N_NODES) hi = N_NODES;
    int s = 0;
    for (int i = lo; i < hi; ++i) s += offsets[i];
    sums[tid] = s;
    __syncthreads();
    if (tid == 0) {
        int acc = 0;
        for (int i = 0; i < T; ++i) { int v = sums[i]; sums[i] = acc; acc += v; }
    }
    __syncthreads();
    int acc = sums[tid];
    for (int i = lo; i < hi; ++i) { int v = offsets[i]; offsets[i] = acc; acc += v; }
}

// after this kernel, offsets[n] == end(n) == start(n+1); start(0)=0
__global__ void k_scatter(const int* __restrict__ dst, int* __restrict__ offsets,
                          int* __restrict__ edge_list) {
    int e = blockIdx.x * blockDim.x + threadIdx.x;
    if (e < N_EDGES) {
        int pos = atomicAdd(&offsets[dst[e]], 1);
        edge_list[pos] = e;
    }
}

// ---------------- main: one block per node, atomic-free output ----------------

__global__ __launch_bounds__(256) void k_main(
    const float* __restrict__ x_nodes, const float* __restrict__ x_edges,
    const float* __restrict__ path_coeffs, const int* __restrict__ src,
    const int* __restrict__ path_indices,
    const int* __restrict__ offsets, const int* __restrict__ edge_list,
    float* __restrict__ out)
{
    __shared__ float x1s[OP_SIZE];
    __shared__ float x2s[OP_SIZE];
    __shared__ float p_coef[N_PATHS];
    __shared__ int   p_i1[N_PATHS], p_i2[N_PATHS];
    __shared__ int   p_start[N_SEG + 1];

    const int tid = threadIdx.x;
    const int n   = blockIdx.x;

    // ---- sort paths by output segment i3 into per-seg lists (tiny) ----
    if (tid < N_SEG) {
        int cnt = 0;
        for (int p = 0; p < N_PATHS; ++p)
            if (path_indices[p * 3 + 2] == tid) ++cnt;
        p_start[tid + 1] = cnt;
    }
    if (tid == 0) p_start[0] = 0;
    __syncthreads();
    if (tid == 0)
        for (int s = 0; s < N_SEG; ++s) p_start[s + 1] += p_start[s];
    __syncthreads();
    if (tid < N_SEG) {
        int w = p_start[tid];
        for (int p = 0; p < N_PATHS; ++p) {
            if (path_indices[p * 3 + 2] == tid) {
                p_i1[w]   = path_indices[p * 3 + 0];
                p_i2[w]   = path_indices[p * 3 + 1];
                p_coef[w] = path_coeffs[p];
                ++w;
            }
        }
    }
    __syncthreads();

    const int start = (n == 0) ? 0 : offsets[n - 1];
    const int end   = offsets[n];

    const int xl = tid & 31;   // extent lane
    const int s0 = tid >> 5;   // segment 0..7 (also handles s0+8)
    float acc0 = 0.f, acc1 = 0.f;

    for (int ei = start; ei < end; ++ei) {
        const int e  = edge_list[ei];
        const int sn = src[e];
        // stage x1 (node row) and x2 (edge row) into LDS: 16B/lane, coalesced
        const float4* x1g = (const float4*)(x_nodes + (size_t)sn * OP_SIZE);
        const float4* x2g = (const float4*)(x_edges + (size_t)e  * OP_SIZE);
        if (tid < 128) ((float4*)x1s)[tid]       = x1g[tid];
        else           ((float4*)x2s)[tid - 128] = x2g[tid - 128];
        __syncthreads();

        {
            float a = 0.f;
            for (int k = p_start[s0]; k < p_start[s0 + 1]; ++k)
                a += p_coef[k] * x1s[p_i1[k] * EXTENT + xl] * x2s[p_i2[k] * EXTENT + xl];
            acc0 += a;
        }
        {
            const int s = s0 + 8;
            float a = 0.f;
            for (int k = p_start[s]; k < p_start[s + 1]; ++k)
                a += p_coef[k] * x1s[p_i1[k] * EXTENT + xl] * x2s[p_i2[k] * EXTENT + xl];
            acc1 += a;
        }
        __syncthreads();
    }

    const size_t ob = (size_t)n * OP_SIZE;
    out[ob + tid]       = acc0;   // tid == s0*32+xl
    out[ob + tid + 256] = acc1;   // (s0+8)*32+xl
}

// ---------------- launch ----------------

extern "C" void kernel_launch(void* const* d_in, const int* in_sizes, int n_in,
                              void* d_out, int out_size, void* d_ws, size_t ws_size,
                              hipStream_t stream) {
    const float* x_nodes      = (const float*)d_in[0];
    const float* x_edges      = (const float*)d_in[1];
    const float* path_coeffs  = (const float*)d_in[2];
    const int*   src          = (const int*)d_in[3];
    const int*   dst          = (const int*)d_in[4];
    const int*   path_indices = (const int*)d_in[5];
    float* out = (float*)d_out;

    int* offsets   = (int*)d_ws;            // N_NODES ints
    int* edge_list = offsets + N_NODES;     // N_EDGES ints

    hipMemsetAsync(d_ws, 0, N_NODES * sizeof(int), stream);
    k_hist   <<<(N_EDGES + 255) / 256, 256, 0, stream>>>(dst, offsets);
    k_scan   <<<1, 256, 0, stream>>>(offsets);
    k_scatter<<<(N_EDGES + 255) / 256, 256, 0, stream>>>(dst, offsets, edge_list);
    k_main   <<<N_NODES, 256, 0, stream>>>(x_nodes, x_edges, path_coeffs, src,
                                           path_indices, offsets, edge_list, out);
}

// Round 2
// 768.660 us; speedup vs baseline: 1.0289x; 1.0289x over previous
//
#include <hip/hip_runtime.h>
#include <stdint.h>

#define N_NODES  20000
#define N_EDGES  200000
#define N_SEG    16
#define EXTENT   32
#define N_PATHS  64
#define OP_SIZE  (N_SEG * EXTENT)   // 512

// ---------------- CSR build: histogram -> scan -> scatter ----------------

__global__ void k_hist(const int* __restrict__ dst, int* __restrict__ offsets) {
    int e = blockIdx.x * blockDim.x + threadIdx.x;
    if (e < N_EDGES) atomicAdd(&offsets[dst[e]], 1);
}

// single block, in-place exclusive scan of offsets[0..N_NODES)
__global__ void k_scan(int* __restrict__ offsets) {
    __shared__ int sums[256];
    const int T = 256;
    int tid = threadIdx.x;
    int chunk = (N_NODES + T - 1) / T;            // 79
    int lo = tid * chunk;
    int hi = lo + chunk; if (hi > N_NODES) hi = N_NODES;
    int s = 0;
    for (int i = lo; i < hi; ++i) s += offsets[i];
    sums[tid] = s;
    __syncthreads();
    if (tid == 0) {
        int acc = 0;
        for (int i = 0; i < T; ++i) { int v = sums[i]; sums[i] = acc; acc += v; }
    }
    __syncthreads();
    int acc = sums[tid];
    for (int i = lo; i < hi; ++i) { int v = offsets[i]; offsets[i] = acc; acc += v; }
}

// after this kernel, offsets[n] == end(n); start(n) = offsets[n-1], start(0)=0
__global__ void k_scatter(const int* __restrict__ dst, int* __restrict__ offsets,
                          int* __restrict__ edge_list) {
    int e = blockIdx.x * blockDim.x + threadIdx.x;
    if (e < N_EDGES) {
        int pos = atomicAdd(&offsets[dst[e]], 1);
        edge_list[pos] = e;
    }
}

// ---------------- path table: counting-sort by output segment i3 ----------------
// rec[k].x = (i1*EXTENT)<<16 | (i2*EXTENT)   (float offsets within a row)
// rec[k].y = bitcast(coef)
__global__ void k_paths(const int* __restrict__ path_indices,
                        const float* __restrict__ path_coeffs,
                        int* __restrict__ pstart, int2* __restrict__ rec) {
    if (threadIdx.x == 0 && blockIdx.x == 0) {
        int cnt[N_SEG + 1];
        for (int i = 0; i <= N_SEG; ++i) cnt[i] = 0;
        for (int p = 0; p < N_PATHS; ++p) cnt[path_indices[p * 3 + 2] + 1]++;
        for (int i = 0; i < N_SEG; ++i) cnt[i + 1] += cnt[i];
        for (int i = 0; i <= N_SEG; ++i) pstart[i] = cnt[i];
        int cur[N_SEG];
        for (int i = 0; i < N_SEG; ++i) cur[i] = cnt[i];
        for (int p = 0; p < N_PATHS; ++p) {
            int s3 = path_indices[p * 3 + 2];
            int w = cur[s3]++;
            int2 r;
            r.x = ((path_indices[p * 3 + 0] * EXTENT) << 16) |
                   (path_indices[p * 3 + 1] * EXTENT);
            r.y = __float_as_int(path_coeffs[p]);
            rec[w] = r;
        }
    }
}

// ---------------- main: one WAVE per node, barrier-free ----------------

__device__ __forceinline__ void async16(const float* g, float* l) {
    // lane i's 16B -> wave-uniform LDS base + i*16
    __builtin_amdgcn_global_load_lds(
        (const __attribute__((address_space(1))) uint32_t*)g,
        (__attribute__((address_space(3))) uint32_t*)l, 16, 0, 0);
}

__global__ __launch_bounds__(256, 4) void k_main(
    const float* __restrict__ x_nodes, const float* __restrict__ x_edges,
    const int* __restrict__ src,
    const int* __restrict__ offsets, const int* __restrict__ edge_list,
    const int* __restrict__ pstart, const int2* __restrict__ rec,
    float* __restrict__ out)
{
    // per-wave private LDS: [x1A(512) | x2A(512) | x1B(512) | x2B(512)] floats
    __shared__ float lds[4 * 2048];

    const int wid  = __builtin_amdgcn_readfirstlane(threadIdx.x >> 6);
    const int lane = threadIdx.x & 63;
    const int xl   = lane & 31;
    const int h    = lane >> 5;          // 0 = edge A, 1 = edge B
    const int wb   = wid << 11;          // wid * 2048 floats

    const int n = blockIdx.x * 4 + wid;  // node for this wave

    // hoist path-segment starts into registers (uniform -> SGPRs)
    int ks[N_SEG + 1];
#pragma unroll
    for (int i = 0; i <= N_SEG; ++i) ks[i] = pstart[i];

    const int start = (n == 0) ? 0 : offsets[n - 1];
    const int end   = offsets[n];

    float acc[N_SEG];
#pragma unroll
    for (int s = 0; s < N_SEG; ++s) acc[s] = 0.f;

    float* lA1 = lds + wb;
    float* lA2 = lds + wb + 512;
    float* lB1 = lds + wb + 1024;
    float* lB2 = lds + wb + 1536;
    const float* b1 = lds + wb + (h << 10);   // this lane's x1 buffer
    const float* b2 = b1 + 512;               // this lane's x2 buffer

    for (int ei = start; ei < end; ei += 2) {
        const int eA  = edge_list[ei];
        const int snA = src[eA];
        const float* gA1 = x_nodes + (size_t)snA * OP_SIZE + lane * 4;
        const float* gA2 = x_edges + (size_t)eA  * OP_SIZE + lane * 4;
        async16(gA1,       lA1);
        async16(gA1 + 256, lA1 + 256);
        async16(gA2,       lA2);
        async16(gA2 + 256, lA2 + 256);

        if (ei + 1 < end) {
            const int eB  = edge_list[ei + 1];
            const int snB = src[eB];
            const float* gB1 = x_nodes + (size_t)snB * OP_SIZE + lane * 4;
            const float* gB2 = x_edges + (size_t)eB  * OP_SIZE + lane * 4;
            async16(gB1,       lB1);
            async16(gB1 + 256, lB1 + 256);
            async16(gB2,       lB2);
            async16(gB2 + 256, lB2 + 256);
        } else {
            // zero x1B+x2B (1024 floats) so half-1 lanes contribute 0
            float4 z = make_float4(0.f, 0.f, 0.f, 0.f);
            float4* zb = (float4*)lB1;
            zb[lane]       = z;
            zb[lane + 64]  = z;
            zb[lane + 128] = z;
            zb[lane + 192] = z;
        }

        // wave-level wait: vmcnt(0) (global_load_lds) + lgkmcnt(0) (zero-fill)
        __builtin_amdgcn_s_waitcnt(0x0070);
        __builtin_amdgcn_sched_barrier(0);

#pragma unroll
        for (int s = 0; s < N_SEG; ++s) {
            float a = acc[s];
            for (int k = ks[s]; k < ks[s + 1]; ++k) {
                int2 r = rec[k];                        // uniform -> s_load_dwordx2
                a = fmaf(__int_as_float(r.y),
                         b1[(r.x >> 16) + xl] * b2[(r.x & 0xffff) + xl], a);
            }
            acc[s] = a;
        }
    }

    // combine halves: lane l and l^32 hold partials of the same outputs
#pragma unroll
    for (int s = 0; s < N_SEG; ++s) acc[s] += __shfl_xor(acc[s], 32);

    float* row = out + (size_t)n * OP_SIZE;
#pragma unroll
    for (int j = 0; j < 8; ++j)
        row[j * 64 + lane] = h ? acc[2 * j + 1] : acc[2 * j];   // seg = 2j+h
}

// ---------------- launch ----------------

extern "C" void kernel_launch(void* const* d_in, const int* in_sizes, int n_in,
                              void* d_out, int out_size, void* d_ws, size_t ws_size,
                              hipStream_t stream) {
    const float* x_nodes      = (const float*)d_in[0];
    const float* x_edges      = (const float*)d_in[1];
    const float* path_coeffs  = (const float*)d_in[2];
    const int*   src          = (const int*)d_in[3];
    const int*   dst          = (const int*)d_in[4];
    const int*   path_indices = (const int*)d_in[5];
    float* out = (float*)d_out;

    int*  offsets   = (int*)d_ws;                 // N_NODES ints
    int*  edge_list = offsets + N_NODES;          // N_EDGES ints
    int2* rec       = (int2*)(edge_list + N_EDGES); // 64 int2 (8B-aligned)
    int*  pstart    = (int*)(rec + N_PATHS);      // 17 ints

    hipMemsetAsync(offsets, 0, N_NODES * sizeof(int), stream);
    k_hist   <<<(N_EDGES + 255) / 256, 256, 0, stream>>>(dst, offsets);
    k_scan   <<<1, 256, 0, stream>>>(offsets);
    k_scatter<<<(N_EDGES + 255) / 256, 256, 0, stream>>>(dst, offsets, edge_list);
    k_paths  <<<1, 64, 0, stream>>>(path_indices, path_coeffs, pstart, rec);
    k_main   <<<N_NODES / 4, 256, 0, stream>>>(x_nodes, x_edges, src,
                                               offsets, edge_list, pstart, rec, out);
}

// Round 3
// 725.628 us; speedup vs baseline: 1.0899x; 1.0593x over previous
//
#include <hip/hip_runtime.h>
#include <stdint.h>

#define N_NODES  20000
#define N_EDGES  200000
#define N_SEG    16
#define EXTENT   32
#define N_PATHS  64
#define OP_SIZE  (N_SEG * EXTENT)   // 512

// s_waitcnt imm (gfx9): vmcnt[3:0]=b3:0, expcnt=b6:4, lgkmcnt=b11:8, vmcnt[5:4]=b15:14
#define WAIT_VM0  0x0F70   // vmcnt(0), lgkm/exp no-wait
#define WAIT_VM4  0x0F74   // vmcnt(4), lgkm/exp no-wait

// ---------------- CSR build ----------------

__global__ void k_hist(const int* __restrict__ dst, int* __restrict__ offsets) {
    int e = blockIdx.x * blockDim.x + threadIdx.x;
    if (e < N_EDGES) atomicAdd(&offsets[dst[e]], 1);
}

// single block, 1024 threads, LDS-staged exclusive scan (coalesced global I/O)
__global__ __launch_bounds__(1024) void k_scan(int* __restrict__ offsets) {
    __shared__ int buf[N_NODES];     // 80 KB
    __shared__ int wsum[16];
    const int tid = threadIdx.x;
    for (int i = tid; i < N_NODES; i += 1024) buf[i] = offsets[i];
    __syncthreads();
    const int C = (N_NODES + 1023) / 1024;   // 20
    int lo = tid * C;
    int hi = lo + C; if (hi > N_NODES) hi = N_NODES; if (lo > N_NODES) lo = N_NODES;
    int s = 0;
    for (int i = lo; i < hi; ++i) s += buf[i];
    // wave-level inclusive scan of per-thread sums
    const int lane = tid & 63, w = tid >> 6;
    int v = s;
    for (int d = 1; d < 64; d <<= 1) { int t = __shfl_up(v, d); if (lane >= d) v += t; }
    if (lane == 63) wsum[w] = v;
    __syncthreads();                  // sums done, wsum visible, safe to overwrite buf
    int wpre = 0;
    for (int q = 0; q < w; ++q) wpre += wsum[q];
    int acc = wpre + v - s;           // exclusive prefix for this thread's chunk
    for (int i = lo; i < hi; ++i) { int t = buf[i]; buf[i] = acc; acc += t; }
    __syncthreads();
    for (int i = tid; i < N_NODES; i += 1024) offsets[i] = buf[i];
}

// after scatter, offsets[n] == end(n); start(n) = offsets[n-1], start(0) = 0
__global__ void k_scatter(const int* __restrict__ dst, const int* __restrict__ src,
                          int* __restrict__ offsets, int2* __restrict__ el2) {
    int e = blockIdx.x * blockDim.x + threadIdx.x;
    if (e < N_EDGES) {
        int pos = atomicAdd(&offsets[dst[e]], 1);
        el2[pos] = make_int2(e, src[e]);   // {edge id, src node}
    }
}

// ---------------- path table ----------------
// Segs sorted by count desc, paired adjacently (minimizes sum of max-lengths).
// Slot t: h=0 half computes seg order[2t], h=1 half seg order[2t+1].
// rec2[k]: .x = lo-half packed offsets (i1*32)<<16 | i2*32, .y = lo coef bits,
//          .z/.w = hi-half.  Padded entries have coef = 0.
__global__ void k_paths(const int* __restrict__ pi, const float* __restrict__ pc,
                        int* __restrict__ ks2g, int4* __restrict__ rec2,
                        int* __restrict__ segmap) {
    __shared__ int   s_i1[N_PATHS], s_i2[N_PATHS], s_i3[N_PATHS];
    __shared__ float s_c[N_PATHS];
    __shared__ int4  s_rec[N_PATHS];
    __shared__ int   s_total;
    const int p = threadIdx.x;   // 64 threads
    s_i1[p] = pi[3 * p]; s_i2[p] = pi[3 * p + 1]; s_i3[p] = pi[3 * p + 2];
    s_c[p]  = pc[p];
    __syncthreads();
    if (p == 0) {
        int cnt[N_SEG];
        for (int s = 0; s < N_SEG; ++s) cnt[s] = 0;
        for (int q = 0; q < N_PATHS; ++q) cnt[s_i3[q]]++;
        int order[N_SEG];
        for (int s = 0; s < N_SEG; ++s) order[s] = s;
        for (int a = 1; a < N_SEG; ++a) {           // insertion sort, count desc
            int o = order[a], b = a;
            while (b > 0 && cnt[order[b - 1]] < cnt[o]) { order[b] = order[b - 1]; --b; }
            order[b] = o;
        }
        int ks[9]; ks[0] = 0;
        for (int t = 0; t < 8; ++t) {
            int slo = order[2 * t], shi = order[2 * t + 1];
            segmap[t] = slo; segmap[8 + t] = shi;
            int L = cnt[slo] > cnt[shi] ? cnt[slo] : cnt[shi];
            int wlo = ks[t], whi = ks[t];
            for (int r = 0; r < L; ++r) { int4 z = {0, 0, 0, 0}; s_rec[ks[t] + r] = z; }
            for (int q = 0; q < N_PATHS; ++q) {
                if (s_i3[q] == slo) {
                    s_rec[wlo].x = ((s_i1[q] * EXTENT) << 16) | (s_i2[q] * EXTENT);
                    s_rec[wlo].y = __float_as_int(s_c[q]); ++wlo;
                }
                if (s_i3[q] == shi) {
                    s_rec[whi].z = ((s_i1[q] * EXTENT) << 16) | (s_i2[q] * EXTENT);
                    s_rec[whi].w = __float_as_int(s_c[q]); ++whi;
                }
            }
            ks[t + 1] = ks[t] + L;
        }
        for (int t = 0; t < 9; ++t) ks2g[t] = ks[t];
        s_total = ks[8];
    }
    __syncthreads();
    if (p < s_total) rec2[p] = s_rec[p];
}

// ---------------- main: 1 wave/node, 1 edge/iter, 2-deep pipelined ----------------

__device__ __forceinline__ void async16(const float* g, float* l) {
    // per-lane 16B global -> wave-uniform LDS base + lane*16
    __builtin_amdgcn_global_load_lds(
        (const __attribute__((address_space(1))) uint32_t*)g,
        (__attribute__((address_space(3))) uint32_t*)l, 16, 0, 0);
}

__device__ __forceinline__ void stage(const float* __restrict__ x_nodes,
                                      const float* __restrict__ x_edges,
                                      int2 m, float* l, int lane) {
    const float* gn = x_nodes + (size_t)m.y * OP_SIZE + lane * 4;
    const float* ge = x_edges + (size_t)m.x * OP_SIZE + lane * 4;
    async16(gn,       l);
    async16(gn + 256, l + 256);
    async16(ge,       l + 512);
    async16(ge + 256, l + 768);
}

__global__ __launch_bounds__(64, 5) void k_main(
    const float* __restrict__ x_nodes, const float* __restrict__ x_edges,
    const int* __restrict__ offsets, const int2* __restrict__ el2,
    const int* __restrict__ ks2g, const int4* __restrict__ rec2,
    const int* __restrict__ segmap, float* __restrict__ out)
{
    __shared__ float lds[2 * 1024];   // 2 sets x (x1 row 512 | x2 row 512) = 8 KB

    const int lane = threadIdx.x;     // 0..63
    const int xl   = lane & 31;
    const int h    = lane >> 5;       // seg-half
    const int n    = blockIdx.x;

    int ks2[9];
#pragma unroll
    for (int j = 0; j < 9; ++j) ks2[j] = ks2g[j];
    int myseg[8];
#pragma unroll
    for (int j = 0; j < 8; ++j) myseg[j] = segmap[h * 8 + j];

    const int start = (n == 0) ? 0 : offsets[n - 1];
    const int end   = offsets[n];
    const int deg   = end - start;

    float acc[8];
#pragma unroll
    for (int j = 0; j < 8; ++j) acc[j] = 0.f;

    // prologue: issue edges 0 and 1, prefetch meta for edge 2
    int2 mq = make_int2(0, 0);
    if (deg > 0) stage(x_nodes, x_edges, el2[start],     lds,        lane);
    if (deg > 1) stage(x_nodes, x_edges, el2[start + 1], lds + 1024, lane);
    if (deg > 2) mq = el2[start + 2];   // meta for the issue at end of iter 0

    for (int i = 0; i < deg; ++i) {
        // prefetch meta for edge i+3 (consumed at end of iter i+1) — issued
        // BEFORE stage(i+2) so the compiler's dep-wait on it never drains the pipe
        int2 mf = make_int2(0, 0);
        if (i + 3 < deg) mf = el2[start + i + 3];

        // edge i's 4 staging loads are the oldest outstanding; leave edge i+1's in flight
        if (i + 1 < deg) __builtin_amdgcn_s_waitcnt(WAIT_VM4);
        else             __builtin_amdgcn_s_waitcnt(WAIT_VM0);
        __builtin_amdgcn_sched_barrier(0);

        const float* b1 = lds + ((i & 1) << 10);        // x_nodes row
        const float* b2 = b1 + 512;                     // x_edges row
#pragma unroll
        for (int j = 0; j < 8; ++j) {
            float a = acc[j];
            for (int k = ks2[j]; k < ks2[j + 1]; ++k) {
                int4 r = rec2[k];                       // uniform -> scalar load
                int   off = h ? r.z : r.x;
                float cf  = __int_as_float(h ? r.w : r.y);
                a = fmaf(cf, b1[(off >> 16) + xl] * b2[(off & 0xffff) + xl], a);
            }
            acc[j] = a;
        }

        // overwrite this set with edge i+2 (ds_reads above already executed;
        // DMA arrival is >> LDS-pipe depth, no hazard)
        if (i + 2 < deg) {
            stage(x_nodes, x_edges, mq, lds + ((i & 1) << 10), lane);
            mq = mf;
        }
    }

    float* row = out + (size_t)n * OP_SIZE;
#pragma unroll
    for (int j = 0; j < 8; ++j)
        row[myseg[j] * EXTENT + xl] = acc[j];
}

// ---------------- launch ----------------

extern "C" void kernel_launch(void* const* d_in, const int* in_sizes, int n_in,
                              void* d_out, int out_size, void* d_ws, size_t ws_size,
                              hipStream_t stream) {
    const float* x_nodes      = (const float*)d_in[0];
    const float* x_edges      = (const float*)d_in[1];
    const float* path_coeffs  = (const float*)d_in[2];
    const int*   src          = (const int*)d_in[3];
    const int*   dst          = (const int*)d_in[4];
    const int*   path_indices = (const int*)d_in[5];
    float* out = (float*)d_out;

    char* ws = (char*)d_ws;
    int*  offsets = (int*)ws;                          ws += N_NODES * sizeof(int);   // 80000
    int2* el2     = (int2*)ws;                         ws += N_EDGES * sizeof(int2);  // 1.6 MB
    int4* rec2    = (int4*)ws;                         ws += N_PATHS * sizeof(int4);
    int*  ks2g    = (int*)ws;                          ws += 16 * sizeof(int);
    int*  segmap  = (int*)ws;

    hipMemsetAsync(offsets, 0, N_NODES * sizeof(int), stream);
    k_hist   <<<(N_EDGES + 255) / 256, 256, 0, stream>>>(dst, offsets);
    k_scan   <<<1, 1024, 0, stream>>>(offsets);
    k_scatter<<<(N_EDGES + 255) / 256, 256, 0, stream>>>(dst, src, offsets, el2);
    k_paths  <<<1, 64, 0, stream>>>(path_indices, path_coeffs, ks2g, rec2, segmap);
    k_main   <<<N_NODES, 64, 0, stream>>>(x_nodes, x_edges, offsets, el2,
                                          ks2g, rec2, segmap, out);
}